// Round 15
// baseline (139.577 us; speedup 1.0000x reference)
//
#include <hip/hip_runtime.h>
#include <math.h>

#define BATCH 4
#define NPTS 4096
#define DF 64
#define ROWB 128               // bytes per point row in bf16
#define TILE 128               // col tile per iter
#define MC 4                   // col chunks
#define CHUNK (NPTS / MC)      // 1024
#define ITERS (CHUNK / TILE)   // 8
#define INV_T 100.0f
#define MARGIN 0.16f           // gate margin: skipped weights < e^-16 vs final min
#define RTHR 0.08f             // rescale when running min improves by > RTHR
#define SCALE (1.0f / 16384.0f)

typedef float  f32x4 __attribute__((ext_vector_type(4)));
typedef short  s16x8 __attribute__((ext_vector_type(8)));
typedef unsigned short u16;

// ws layout (6.19 MB, proven)
#define SZ_B   (BATCH * NPTS * DF * 2)   // bf16 array: 2 MB
#define SZ_N   (BATCH * NPTS * 4)        // norm array: 64 KB
#define OFF_XB 0
#define OFF_YB (OFF_XB + SZ_B)
#define OFF_X2 (OFF_YB + SZ_B)
#define OFF_Y2 (OFF_X2 + SZ_N)
#define OFF_PART (OFF_Y2 + SZ_N)         // [dirb][MC][NPTS][4] floats: 2 MB

__device__ __forceinline__ u16 f2bf(float f) {
    unsigned u = __float_as_uint(f);
    unsigned r = (u + 0x7fffu + ((u >> 16) & 1u)) >> 16;   // RNE
    return (u16)r;
}

// async 16B global -> LDS (DMA, no VGPR round-trip)
__device__ __forceinline__ void async16(void* lds, const void* g) {
    __builtin_amdgcn_global_load_lds(
        (const __attribute__((address_space(1))) unsigned int*)g,
        (__attribute__((address_space(3))) unsigned int*)lds, 16, 0, 0);
}

// fp32 -> bf16 (XOR-swizzled row layout: byte ^= (point&7)<<4) + fp32 norms.
__global__ __launch_bounds__(256) void prep_kernel(const float* __restrict__ X,
                                                   const float* __restrict__ Y,
                                                   u16* __restrict__ xb, u16* __restrict__ yb,
                                                   float* __restrict__ x2, float* __restrict__ y2,
                                                   float* __restrict__ out) {
    if (blockIdx.x == 0 && blockIdx.y == 0 && threadIdx.x == 0) out[0] = 0.0f;
    const float* src = blockIdx.y ? Y : X;
    u16* dstb   = blockIdx.y ? yb : xb;
    float* dstn = blockIdx.y ? y2 : x2;
    int g = blockIdx.x * 256 + threadIdx.x;
    int p = g >> 4;                       // point 0..16383
    int sub = g & 15;                     // 8B chunk within row
    float4 v = ((const float4*)src)[(size_t)p * 16 + sub];
    float n4 = v.x * v.x + v.y * v.y + v.z * v.z + v.w * v.w;
    #pragma unroll
    for (int m = 1; m < 16; m <<= 1) n4 += __shfl_xor(n4, m, 16);
    ushort4 hh;
    hh.x = f2bf(v.x); hh.y = f2bf(v.y); hh.z = f2bf(v.z); hh.w = f2bf(v.w);
    int byteoff = (sub << 3) ^ ((p & 7) << 4);   // swizzle (XOR bits 4..6)
    *(ushort4*)((char*)dstb + (size_t)p * ROWB + byteoff) = hh;
    if (sub == 0) dstn[p] = n4;
}

// SINGLE-PASS online partial softmin. Block = 64 rows x 1024 cols, wave
// tiling 2x2 (wave: 32 rows x 64 cols/tile). MFMA C seeded with -y2/2 so
// u = acc[r]. Per (st,r): running reference dref (lane-group uniform),
// gate d < dref+MARGIN, deferred rescale when min improves by > RTHR.
// All accumulated weights <= e^8 by construction (rescale-before-accumulate).
__global__ __launch_bounds__(256) void softmin_fused(const u16* __restrict__ xb,
                                                     const u16* __restrict__ yb,
                                                     const float* __restrict__ x2g,
                                                     const float* __restrict__ y2g,
                                                     float* __restrict__ part) {
    __shared__ u16 ys[2][TILE * DF];     // 2 x 16 KB double buffer
    __shared__ float cyS[CHUNK];         // 4 KB col norms
    __shared__ float xchg[4][32][3];     // cross-wcol {dref,S,T} merge

    const int tid = threadIdx.x;
    const int nt  = blockIdx.x;
    const int b   = blockIdx.y & 3;
    const int cs  = blockIdx.y >> 2;
    const int dir = blockIdx.z;

    const u16 *rowsrc, *colsrc; const float *rn, *cn;
    if (dir == 0) { rowsrc = xb; colsrc = yb; rn = x2g; cn = y2g; }
    else          { rowsrc = yb; colsrc = xb; rn = y2g; cn = x2g; }

    const int w    = tid >> 6;
    const int wrow = w >> 1, wcol = w & 1;
    const int h    = (tid >> 4) & 3;     // k-octet / D-row group
    const int c    = tid & 15;           // fragment lane slot

    const size_t bpts = (size_t)b * NPTS;
    const int row0 = nt * 64;
    const char* rbase = (const char*)(rowsrc + (bpts + row0) * DF);
    const char* cbase = (const char*)(colsrc + (bpts + (size_t)cs * CHUNK) * DF);
    const float* cnb = cn + bpts + (size_t)cs * CHUNK;

    // loop-invariant B fragment offsets + col point ids (4 x 16-col groups)
    int boff[4][2], pty[4];
    #pragma unroll
    for (int ct = 0; ct < 4; ++ct) {
        int p = wcol * 64 + ct * 16 + c;
        pty[ct] = p;
        #pragma unroll
        for (int kp = 0; kp < 2; ++kp)
            boff[ct][kp] = p * ROWB + ((h * 16 + kp * 64) ^ ((p & 7) << 4));
    }

    // ---- prologue: DMA first y tile; stage col norms; A-frags from global ----
    #pragma unroll
    for (int q = 0; q < 4; ++q) {
        int e = q * 256 + tid;
        async16((char*)ys[0] + e * 16, cbase + e * 16);
    }
    *(float4*)&cyS[tid * 4] = ((const float4*)cnb)[tid];   // 1024 col norms

    s16x8 afrag[2][2];
    #pragma unroll
    for (int st = 0; st < 2; ++st) {
        int rr = (wrow * 2 + st) * 16 + c;
        #pragma unroll
        for (int kp = 0; kp < 2; ++kp) {
            int o = (h * 16 + kp * 64) ^ ((rr & 7) << 4);
            afrag[st][kp] = *(const s16x8*)(rbase + rr * ROWB + o);
        }
    }
    float x2v[2][4];
    #pragma unroll
    for (int st = 0; st < 2; ++st)
        #pragma unroll
        for (int r = 0; r < 4; ++r)
            x2v[st][r] = rn[bpts + row0 + (wrow * 2 + st) * 16 + 4 * h + r];

    // online state: per (st,r)
    float dref[2][4], gthr[2][4], ssum[2][4], tsum[2][4];
    #pragma unroll
    for (int st = 0; st < 2; ++st)
        #pragma unroll
        for (int r = 0; r < 4; ++r) {
            dref[st][r] = INFINITY;      // first fire: f=exp(-inf)=0, rs taken
            gthr[st][r] = -INFINITY;     // first batch always fires
            ssum[st][r] = 0.f; tsum[st][r] = 0.f;
        }

    __syncthreads();   // drains DMA + cyS writes

    // ================= SINGLE PASS: online gated softmin ====================
    for (int it = 0; it < ITERS; ++it) {
        if (it > 0) __syncthreads();     // tile(it) DMA drained
        if (it + 1 < ITERS) {            // issue next tile (overlaps compute)
            const char* nsrc = cbase + (size_t)(it + 1) * TILE * ROWB;
            char* nbuf = (char*)ys[(it + 1) & 1];
            #pragma unroll
            for (int q = 0; q < 4; ++q) {
                int e = q * 256 + tid;
                async16(nbuf + e * 16, nsrc + e * 16);
            }
        }
        const char* bptr = (const char*)ys[it & 1];

        #pragma unroll
        for (int ct = 0; ct < 4; ++ct) {
            s16x8 b0 = *(const s16x8*)(bptr + boff[ct][0]);
            s16x8 b1 = *(const s16x8*)(bptr + boff[ct][1]);
            float m0 = -0.5f * cyS[it * TILE + pty[ct]];
            f32x4 seed = {m0, m0, m0, m0};
            #pragma unroll
            for (int st = 0; st < 2; ++st) {
                f32x4 a = __builtin_amdgcn_mfma_f32_16x16x32_bf16(afrag[st][0], b0, seed, 0, 0, 0);
                a = __builtin_amdgcn_mfma_f32_16x16x32_bf16(afrag[st][1], b1, a, 0, 0, 0);
                #pragma unroll
                for (int r = 0; r < 4; ++r) {
                    if (__any(a[r] > gthr[st][r])) {   // d < dref+MARGIN candidate
                        float d2 = fmaf(-2.f, a[r], x2v[st][r]);
                        float d = sqrtf(fmaxf(d2, 0.f));
                        // 16-lane patch min (uniform within the row group)
                        float dm = d;
                        #pragma unroll
                        for (int m = 1; m < 16; m <<= 1)
                            dm = fminf(dm, __shfl_xor(dm, m, 16));
                        // deferred rescale (branchless; exp(0)=1 when not taken)
                        bool rs = (dref[st][r] - dm > RTHR);
                        float nref = rs ? dm : dref[st][r];
                        float f = __expf(INV_T * (nref - dref[st][r]));
                        ssum[st][r] *= f;
                        tsum[st][r] *= f;
                        dref[st][r] = nref;
                        if (rs) {
                            float dt = nref + MARGIN;
                            gthr[st][r] = 0.5f * fmaf(-dt, dt, x2v[st][r]);
                        }
                        // accumulate: e <= e^8 guaranteed (d >= dm >= dref-RTHR)
                        float e = __expf(INV_T * (dref[st][r] - d));
                        ssum[st][r] += e;
                        tsum[st][r] = fmaf(e, d, tsum[st][r]);
                    }
                }
            }
        }
    }

    // butterfly sums within 16 col-lanes (dref already uniform per group)
    #pragma unroll
    for (int st = 0; st < 2; ++st)
        #pragma unroll
        for (int r = 0; r < 4; ++r)
            #pragma unroll
            for (int m = 1; m < 16; m <<= 1) {
                ssum[st][r] += __shfl_xor(ssum[st][r], m, 16);
                tsum[st][r] += __shfl_xor(tsum[st][r], m, 16);
            }

    // cross-wcol reference-aware merge and partial-state write {ref, S, T}
    __syncthreads();
    if (c == 0) {
        #pragma unroll
        for (int st = 0; st < 2; ++st)
            #pragma unroll
            for (int r = 0; r < 4; ++r) {
                int row32 = st * 16 + 4 * h + r;
                xchg[w][row32][0] = dref[st][r];
                xchg[w][row32][1] = ssum[st][r];
                xchg[w][row32][2] = tsum[st][r];
            }
    }
    __syncthreads();
    if (wcol == 0 && c == 0) {
        int dirb = dir * 4 + b;
        #pragma unroll
        for (int st = 0; st < 2; ++st)
            #pragma unroll
            for (int r = 0; r < 4; ++r) {
                int row32 = st * 16 + 4 * h + r;
                float dro = xchg[w + 1][row32][0];
                float So  = xchg[w + 1][row32][1];
                float To  = xchg[w + 1][row32][2];
                float nm = fminf(dref[st][r], dro);
                float e0 = __expf(INV_T * (nm - dref[st][r]));
                float e1 = __expf(INV_T * (nm - dro));
                float S = ssum[st][r] * e0 + So * e1;
                float T = tsum[st][r] * e0 + To * e1;
                int row = row0 + wrow * 32 + row32;
                float* pp = part + (((size_t)(dirb * MC + cs)) * NPTS + row) * 4;
                pp[0] = nm; pp[1] = S; pp[2] = T;
            }
    }
}

// Merge MC partial states per row (reference-consistent), cube, reduce.
__global__ __launch_bounds__(256) void merge_kernel(const float* __restrict__ part,
                                                    float* __restrict__ out) {
    __shared__ float red[4];
    int g = blockIdx.x * 256 + threadIdx.x;   // dirb*4096 + row
    int dirb = g >> 12;
    int row  = g & 4095;
    const float* p0 = part + (((size_t)dirb * MC) * NPTS + row) * 4;
    float mnv[MC], sv[MC], tv[MC];
    float nm = INFINITY;
    #pragma unroll
    for (int k = 0; k < MC; ++k) {
        const float* p = p0 + (size_t)k * NPTS * 4;
        mnv[k] = p[0]; sv[k] = p[1]; tv[k] = p[2];
        nm = fminf(nm, mnv[k]);
    }
    float S = 0.f, T = 0.f;
    #pragma unroll
    for (int k = 0; k < MC; ++k) {
        float cw = __expf(INV_T * (nm - mnv[k]));
        S += sv[k] * cw;
        T += tv[k] * cw;
    }
    float sm = T / S;
    float v = sm * sm * sm * SCALE;
    #pragma unroll
    for (int m = 1; m < 64; m <<= 1) v += __shfl_xor(v, m, 64);
    if ((threadIdx.x & 63) == 0) red[threadIdx.x >> 6] = v;
    __syncthreads();
    if (threadIdx.x == 0) atomicAdd(out, red[0] + red[1] + red[2] + red[3]);
}

extern "C" void kernel_launch(void* const* d_in, const int* in_sizes, int n_in,
                              void* d_out, int out_size, void* d_ws, size_t ws_size,
                              hipStream_t stream) {
    const float* x = (const float*)d_in[0];
    const float* y = (const float*)d_in[1];
    float* out = (float*)d_out;
    char* ws = (char*)d_ws;

    u16* xb = (u16*)(ws + OFF_XB);
    u16* yb = (u16*)(ws + OFF_YB);
    float* x2 = (float*)(ws + OFF_X2);
    float* y2 = (float*)(ws + OFF_Y2);
    float* part = (float*)(ws + OFF_PART);

    prep_kernel<<<dim3(1024, 2), 256, 0, stream>>>(x, y, xb, yb, x2, y2, out);
    softmin_fused<<<dim3(NPTS / 64, 4 * MC, 2), 256, 0, stream>>>(xb, yb, x2, y2, part);
    merge_kernel<<<128, 256, 0, stream>>>(part, out);
}